// Round 9
// baseline (205.203 us; speedup 1.0000x reference)
//
#include <hip/hip_runtime.h>
#include <hip/hip_bf16.h>
#include <math.h>

// Problem constants (B=16, L=256, D=256, K=16384)
#define NROWS 4096               // B*L anchors / z rows
#define KMEM  16384
#define NCAND 20480              // NROWS + KMEM candidates
#define DIM   256                // feature dim
#define TM    128                // anchor rows per block
#define TN    128                // candidate cols per tile
#define BK    64                 // k-depth per LDS stage (bf16)
#define NSLICE 16                // 512 blocks = 2 blocks/CU (64KB LDS)
#define COLS_PER_SLICE (NCAND / NSLICE)       // 1280
#define TILES_PER_SLICE (COLS_PER_SLICE / TN) // 10
#define INV_T  (1.0f / 0.07f)
#define SCALE2 (1.4426950408889634f / 0.07f)  // log2(e)/T
#define LN2    0.6931471805599453f
#define MERGE_STRIDE 33          // conflict-free merge: (tid*33+x)%32 distinct

typedef short  short8 __attribute__((ext_vector_type(8)));  // 8 bf16 (4 VGPRs)
typedef float  f32x4  __attribute__((ext_vector_type(4)));  // MFMA C/D
typedef unsigned short ushort_t;

// RNE float->bf16 (inputs are finite normals; no NaN path needed)
__device__ inline ushort_t f2bf(float x) {
    union { float f; unsigned u; } a; a.f = x;
    unsigned r = a.u + 0x7fff + ((a.u >> 16) & 1);
    return (ushort_t)(r >> 16);
}

// async global->LDS, 16B per lane, dest = wave-uniform base + lane*16
__device__ inline void load_lds16(const void* g, void* l) {
    __builtin_amdgcn_global_load_lds(
        (const __attribute__((address_space(1))) unsigned int*)g,
        (__attribute__((address_space(3))) unsigned int*)l, 16, 0, 0);
}

// pack two fp32 -> bf16x2 (round-half-up) via one v_perm: low16 = bf(a), hi = bf(b)
__device__ inline unsigned pkbf(float a, float b) {
    const unsigned ua = __float_as_uint(a) + 0x8000u;
    const unsigned ub = __float_as_uint(b) + 0x8000u;
    return __builtin_amdgcn_perm(ub, ua, 0x07060302u);  // bytes: a23 b23
}

// Prep kernel (grid 2048): blocks 0..1023 cast z -> z_bf (RNE);
// blocks 1024..2047 compute fp32 pos[i] = dot(z[i],z[i+1])/T (1 wave/row).
// Block 0 also zeroes control words.
__global__ __launch_bounds__(256) void prep_kernel(
    const float* __restrict__ z, ushort_t* __restrict__ z_bf,
    float* __restrict__ pos, unsigned* __restrict__ ctrl)
{
    const int bx = blockIdx.x;
    if (bx == 0 && threadIdx.x < 34) ctrl[threadIdx.x] = 0u;
    if (bx < 1024) {
        const int idx = bx * 256 + threadIdx.x;      // float4 idx < 262144
        const float4 v = ((const float4*)z)[idx];
        ushort4 u; u.x = f2bf(v.x); u.y = f2bf(v.y);
        u.z = f2bf(v.z); u.w = f2bf(v.w);
        ((ushort4*)z_bf)[idx] = u;
    } else {
        const int row  = (bx - 1024) * 4 + ((int)threadIdx.x >> 6);
        const int lane = threadIdx.x & 63;
        if ((row & 255) != 255) {   // valid pair; also guards row 4095
            const float4 av = *(const float4*)(z + (size_t)row * DIM + lane * 4);
            const float4 bv = *(const float4*)(z + (size_t)(row + 1) * DIM + lane * 4);
            float sum = av.x * bv.x + av.y * bv.y + av.z * bv.z + av.w * bv.w;
#pragma unroll
            for (int off = 32; off > 0; off >>= 1) sum += __shfl_down(sum, off);
            if (lane == 0) pos[row] = sum * INV_T;
        }
    }
}

// Kernel A: R5's double-buffered MFMA flash-LSE main loop, cast fused into
// staging (no cand array, no cast kernel):
//  - A-tiles + B-tiles with cols < 4096: async global_load_lds from z_bf.
//  - B-tiles with cols >= 4096: 8 float4 fp32 loads from memory_queue issued
//    BEFORE the stage's MFMAs (latency covered), then v_perm bf16 pack +
//    4x ds_write_b128 into the prefetch buffer. Same LDS/swizzle layout.
// Tail: R8's release/acquire finisher; pos precomputed (16KB read, not 8MB).
__global__ __launch_bounds__(256) void mfma_lse_kernel(
    const ushort_t* __restrict__ z_bf, const float* __restrict__ memf,
    float* __restrict__ part_m, float* __restrict__ part_s,
    const float* __restrict__ pos, unsigned* __restrict__ ctrl,
    float* __restrict__ out)
{
    __shared__ __align__(16) char smem_raw[65536];       // 2x(A 16KB + B 16KB)
    __shared__ int sFlag;
    ushort_t* ldsA = (ushort_t*)smem_raw;                // [2][128*64]
    ushort_t* ldsB = ldsA + 2 * TM * BK;                 // [2][128*64]

    const int tid  = threadIdx.x;
    const int lane = tid & 63;
    const int w    = tid >> 6;        // wave 0..3
    const int wr   = w >> 1;          // wave row half (0/1)
    const int wc   = w & 1;           // wave col half
    const int quad = lane >> 4;
    const int ln   = lane & 15;
    const int bx   = blockIdx.x;
    const int rowBase = bx * TM;
    const int slice   = blockIdx.y;
    const int colSliceBase = slice * COLS_PER_SLICE;

    unsigned* grp  = ctrl;            // [32] row-group arrival counters
    unsigned* done = ctrl + 32;       // group-finisher count
    float*    loss = (float*)(ctrl + 33);

    // Staging geometry (R5, proven): wave w covers tile rows [w*32,w*32+32),
    // lane l -> row srow + u*8, chunk c = (l&7)^(srow&7). XOR swizzle keeps
    // fragment ds_read_b128 conflict-free.
    const int srow = w * 32 + (lane >> 3);
    const int sc   = (lane & 7) ^ (srow & 7);
    const ushort_t* agp = z_bf + (size_t)(rowBase + srow) * DIM + sc * 8;
    ushort_t* lab = ldsA + (w * 32) * BK;   // + buf*TM*BK + u*8*BK
    ushort_t* lbb = ldsB + (w * 32) * BK;

    auto stageA = [&](int kk, int buf) {
        const ushort_t* ag = agp + kk;
        ushort_t* la = lab + buf * (TM * BK);
#pragma unroll
        for (int u = 0; u < 4; ++u)
            load_lds16(ag + u * 8 * DIM, la + u * 8 * BK);
    };
    auto stageBz = [&](int col0, int kk, int buf) {   // whole tile in z region
        const ushort_t* bg = z_bf + (size_t)(col0 + srow) * DIM + sc * 8 + kk;
        ushort_t* lb = lbb + buf * (TM * BK);
#pragma unroll
        for (int u = 0; u < 4; ++u)
            load_lds16(bg + u * 8 * DIM, lb + u * 8 * BK);
    };

    float4 bP[8];                     // fp32 B prefetch (mem-region tiles)
    auto loadBf32 = [&](int col0, int kk) {
        const float* bg = memf + (size_t)(col0 - NROWS + srow) * DIM + sc * 8 + kk;
#pragma unroll
        for (int u = 0; u < 4; ++u) {
            bP[2 * u]     = *(const float4*)(bg + u * 8 * DIM);
            bP[2 * u + 1] = *(const float4*)(bg + u * 8 * DIM + 4);
        }
    };
    auto commitB = [&](int buf) {     // pack + ds_write into prefetch buffer
        ushort_t* lb = lbb + buf * (TM * BK);
#pragma unroll
        for (int u = 0; u < 4; ++u) {
            uint4 qv;
            qv.x = pkbf(bP[2 * u].x,     bP[2 * u].y);
            qv.y = pkbf(bP[2 * u].z,     bP[2 * u].w);
            qv.z = pkbf(bP[2 * u + 1].x, bP[2 * u + 1].y);
            qv.w = pkbf(bP[2 * u + 1].z, bP[2 * u + 1].w);
            *(uint4*)(lb + u * 8 * BK + lane * 8) = qv;
        }
    };

    float m2[16], s[16];
#pragma unroll
    for (int i = 0; i < 16; ++i) { m2[i] = -INFINITY; s[i] = 0.0f; }

    f32x4 acc[4][4];
#pragma unroll
    for (int ti = 0; ti < 4; ++ti)
#pragma unroll
        for (int tj = 0; tj < 4; ++tj) acc[ti][tj] = (f32x4)0.0f;

    // Prologue: stage 0 -> buffer 0 (tiles are 128-aligned; 4096 is a
    // multiple of 128, so each tile is entirely z-region or mem-region).
    {
        const int c0 = colSliceBase;
        stageA(0, 0);
        if (c0 < NROWS) stageBz(c0, 0, 0);
        else { loadBf32(c0, 0); commitB(0); }   // one-time exposed wait
    }
    __syncthreads();

    for (int t = 0; t < TILES_PER_SLICE; ++t) {
#pragma unroll
        for (int q = 0; q < 4; ++q) {
            const int buf = q & 1;          // s = 4t+q -> buf = s&1 = q&1
            const bool hasNext = !(t == TILES_PER_SLICE - 1 && q == 3);
            const int nt  = (q < 3) ? t : t + 1;
            const int nkk = (q < 3) ? (q + 1) * BK : 0;
            const int nc0 = colSliceBase + nt * TN;
            const bool nIsZ = nc0 < NROWS;
            if (hasNext) {
                if (nIsZ) { stageA(nkk, buf ^ 1); stageBz(nc0, nkk, buf ^ 1); }
                else      { loadBf32(nc0, nkk);   stageA(nkk, buf ^ 1); }
                // fp32 B loads issued BEFORE A-asyncs: waiting for bP later
                // leaves the A-asyncs in flight (vmcnt FIFO).
            }

            const ushort_t* la = ldsA + buf * (TM * BK);
            const ushort_t* lb = ldsB + buf * (TM * BK);
#pragma unroll
            for (int ks = 0; ks < 2; ++ks) {
                short8 af[4], bfr[4];
#pragma unroll
                for (int ti = 0; ti < 4; ++ti) {
                    const int row = wr * 64 + ti * 16 + ln;
                    const int p = row * 8 + ((ks * 4 + quad) ^ (row & 7));
                    af[ti] = *(const short8*)(la + p * 8);
                }
#pragma unroll
                for (int tj = 0; tj < 4; ++tj) {
                    const int col = wc * 64 + tj * 16 + ln;
                    const int p = col * 8 + ((ks * 4 + quad) ^ (col & 7));
                    bfr[tj] = *(const short8*)(lb + p * 8);
                }
#pragma unroll
                for (int ti = 0; ti < 4; ++ti)
#pragma unroll
                    for (int tj = 0; tj < 4; ++tj)
                        acc[ti][tj] = __builtin_amdgcn_mfma_f32_16x16x32_bf16(
                            af[ti], bfr[tj], acc[ti][tj], 0, 0, 0);
            }

            // Commit the fp32-path prefetch after MFMAs (loads now landed).
            if (hasNext && !nIsZ) commitB(buf ^ 1);

            if (q == 3) {
                // Per-tile epilogue. C/D layout: col = ln+16*tj+64*wc,
                // row = quad*4+reg+16*ti+64*wr. Mem tiles never hit diagonal.
                const int colBase = colSliceBase + t * TN;
                const bool hasDiag =
                    (colBase < rowBase + TM) && (rowBase < colBase + TN);
#pragma unroll
                for (int ti = 0; ti < 4; ++ti) {
#pragma unroll
                    for (int r = 0; r < 4; ++r) {
                        const int idx = ti * 4 + r;
                        float v0 = acc[ti][0][r], v1 = acc[ti][1][r];
                        float v2 = acc[ti][2][r], v3 = acc[ti][3][r];
                        if (hasDiag) {
                            const int grow = rowBase + wr * 64 + ti * 16 + quad * 4 + r;
                            const int gc0  = colBase + wc * 64 + ln;
                            if (gc0      == grow) v0 = -3.0e38f;  // mask self
                            if (gc0 + 16 == grow) v1 = -3.0e38f;
                            if (gc0 + 32 == grow) v2 = -3.0e38f;
                            if (gc0 + 48 == grow) v3 = -3.0e38f;
                        }
                        const float tmax = fmaxf(fmaxf(v0, v1), fmaxf(v2, v3)) * SCALE2;
                        const float mo = m2[idx];
                        const float mn = fmaxf(mo, tmax);
                        const float sc2 = __builtin_amdgcn_exp2f(mo - mn);
                        s[idx] = s[idx] * sc2
                               + __builtin_amdgcn_exp2f(fmaf(v0, SCALE2, -mn))
                               + __builtin_amdgcn_exp2f(fmaf(v1, SCALE2, -mn))
                               + __builtin_amdgcn_exp2f(fmaf(v2, SCALE2, -mn))
                               + __builtin_amdgcn_exp2f(fmaf(v3, SCALE2, -mn));
                        m2[idx] = mn;
                        acc[ti][0][r] = 0.0f; acc[ti][1][r] = 0.0f;
                        acc[ti][2][r] = 0.0f; acc[ti][3][r] = 0.0f;
                    }
                }
            }
            __syncthreads();   // publishes prefetched stage; frees old buffer
        }
    }

    // Cross-lane merge: 32 partials per row (16 ln x 2 wc), stride-33 overlay.
    float* smf = (float*)smem_raw;         // [128][33] m partials
    float* ssf = smf + TM * MERGE_STRIDE;  // [128][33] s partials
    const int p = wc * 16 + ln;
#pragma unroll
    for (int ti = 0; ti < 4; ++ti)
#pragma unroll
        for (int r = 0; r < 4; ++r) {
            const int rl = wr * 64 + ti * 16 + quad * 4 + r;
            smf[rl * MERGE_STRIDE + p] = m2[ti * 4 + r];
            ssf[rl * MERGE_STRIDE + p] = s[ti * 4 + r];
        }
    __syncthreads();
    if (tid < TM) {
        float M = -INFINITY;
#pragma unroll
        for (int x = 0; x < 32; ++x) M = fmaxf(M, smf[tid * MERGE_STRIDE + x]);
        float S = 0.0f;
#pragma unroll
        for (int x = 0; x < 32; ++x)
            S += ssf[tid * MERGE_STRIDE + x]
               * __builtin_amdgcn_exp2f(smf[tid * MERGE_STRIDE + x] - M);
        // Plain stores; published by the release RMW below.
        part_m[(size_t)(rowBase + tid) * NSLICE + slice] = M;
        part_s[(size_t)(rowBase + tid) * NSLICE + slice] = S;
    }
    __syncthreads();

    // Arrival: release-publish this block's part stores.
    if (tid == 0) {
        const unsigned o = __hip_atomic_fetch_add(
            grp + bx, 1u, __ATOMIC_RELEASE, __HIP_MEMORY_SCOPE_AGENT);
        sFlag = (o == NSLICE - 1);
    }
    __syncthreads();
    if (!sFlag) return;

    // Finisher (1 per row-group): single acquire, then plain loads.
    if (tid == 0)
        (void)__hip_atomic_load(grp + bx, __ATOMIC_ACQUIRE,
                                __HIP_MEMORY_SCOPE_AGENT);
    __syncthreads();   // acquire ordered before the loads below

    float* red = (float*)smem_raw;         // [256] reduction
    float local = 0.0f;
    if (tid < TM) {
        const int row = rowBase + tid;
        if ((row & 255) != 255) {
            const float4* pm4 = (const float4*)(part_m + (size_t)row * NSLICE);
            const float4* ps4 = (const float4*)(part_s + (size_t)row * NSLICE);
            float pm[NSLICE], ps[NSLICE];
#pragma unroll
            for (int x = 0; x < 4; ++x) {
                const float4 mv = pm4[x], sv = ps4[x];
                pm[x*4+0]=mv.x; pm[x*4+1]=mv.y; pm[x*4+2]=mv.z; pm[x*4+3]=mv.w;
                ps[x*4+0]=sv.x; ps[x*4+1]=sv.y; ps[x*4+2]=sv.z; ps[x*4+3]=sv.w;
            }
            float M = -INFINITY, S = 0.0f;
#pragma unroll
            for (int x = 0; x < NSLICE; ++x) M = fmaxf(M, pm[x]);
#pragma unroll
            for (int x = 0; x < NSLICE; ++x)
                S += ps[x] * __builtin_amdgcn_exp2f(pm[x] - M);
            const float lse = LN2 * (M + __builtin_amdgcn_logf(S));
            local = lse - pos[row];        // pos precomputed by prep kernel
        }
    }
    red[tid] = local;
    __syncthreads();
    for (int st = 128; st > 0; st >>= 1) {
        if (tid < st) red[tid] += red[tid + st];
        __syncthreads();
    }
    if (tid == 0) {
        atomicAdd(loss, red[0]);           // device-scope float atomic
        const unsigned od = __hip_atomic_fetch_add(
            done, 1u, __ATOMIC_ACQ_REL, __HIP_MEMORY_SCOPE_AGENT);
        if (od == NROWS / TM - 1) {
            const float total = __hip_atomic_load(loss, __ATOMIC_RELAXED,
                                                  __HIP_MEMORY_SCOPE_AGENT);
            out[0] = total / 4080.0f;      // B*(L-1) valid pairs
        }
    }
}

extern "C" void kernel_launch(void* const* d_in, const int* in_sizes, int n_in,
                              void* d_out, int out_size, void* d_ws, size_t ws_size,
                              hipStream_t stream) {
    const float* z   = (const float*)d_in[0];   // [4096, 256]
    // d_in[1] = va_values: dead code in the reference, unused.
    const float* mem = (const float*)d_in[2];   // [16384, 256]

    // ws layout: z_bf bf16 [4096*256] | part_m f32 [4096*16]
    //          | part_s f32 [4096*16] | pos f32 [4096] | ctrl u32 [64]
    ushort_t* z_bf = (ushort_t*)d_ws;
    float* part_m  = (float*)(z_bf + (size_t)NROWS * DIM);
    float* part_s  = part_m + (size_t)NROWS * NSLICE;
    float* pos     = part_s + (size_t)NROWS * NSLICE;
    unsigned* ctrl = (unsigned*)(pos + NROWS);

    prep_kernel<<<dim3(2048), dim3(256), 0, stream>>>(z, z_bf, pos, ctrl);
    mfma_lse_kernel<<<dim3(NROWS / TM, NSLICE), dim3(256), 0, stream>>>(
        z_bf, mem, part_m, part_s, pos, ctrl, (float*)d_out);
}

// Round 10
// 143.108 us; speedup vs baseline: 1.4339x; 1.4339x over previous
//
#include <hip/hip_runtime.h>
#include <hip/hip_bf16.h>
#include <math.h>

// Problem constants (B=16, L=256, D=256, K=16384)
#define NROWS 4096               // B*L anchors / z rows
#define KMEM  16384
#define NCAND 20480              // NROWS + KMEM candidates
#define DIM   256                // feature dim
#define TM    128                // anchor rows per block
#define TN    128                // candidate cols per tile
#define BK    64                 // k-depth per LDS stage (bf16)
#define NSLICE 16                // 512 blocks = 2 blocks/CU (64KB LDS)
#define COLS_PER_SLICE (NCAND / NSLICE)       // 1280
#define TILES_PER_SLICE (COLS_PER_SLICE / TN) // 10
#define INV_T  (1.0f / 0.07f)
#define SCALE2 (1.4426950408889634f / 0.07f)  // log2(e)/T
#define LN2    0.6931471805599453f
#define MERGE_STRIDE 33          // conflict-free merge: (tid*33+x)%32 distinct

typedef short  short8 __attribute__((ext_vector_type(8)));  // 8 bf16 (4 VGPRs)
typedef float  f32x4  __attribute__((ext_vector_type(4)));  // MFMA C/D
typedef unsigned short ushort_t;

// RNE float->bf16 (inputs are finite normals; no NaN path needed)
__device__ inline ushort_t f2bf(float x) {
    union { float f; unsigned u; } a; a.f = x;
    unsigned r = a.u + 0x7fff + ((a.u >> 16) & 1);
    return (ushort_t)(r >> 16);
}

// async global->LDS, 16B per lane, dest = wave-uniform base + lane*16
__device__ inline void load_lds16(const void* g, void* l) {
    __builtin_amdgcn_global_load_lds(
        (const __attribute__((address_space(1))) unsigned int*)g,
        (__attribute__((address_space(3))) unsigned int*)l, 16, 0, 0);
}

// Prep kernel (grid 6144): blocks 0..5119 cast [z;mem] fp32 -> cand bf16;
// blocks 5120..6143 compute fp32 pos[i] = dot(z[i],z[i+1])/T (1 wave/row).
// Block 0 zeroes control words (kernel boundary orders it for the mfma kernel).
__global__ __launch_bounds__(256) void prep_kernel(
    const float* __restrict__ z, const float* __restrict__ mem,
    ushort_t* __restrict__ cand, float* __restrict__ pos,
    unsigned* __restrict__ ctrl)
{
    const int bx = blockIdx.x;
    if (bx == 0 && threadIdx.x < 34) ctrl[threadIdx.x] = 0u;
    if (bx < 5120) {
        const int idx = bx * 256 + threadIdx.x;      // float4 idx < 1310720
        const int ZQ = NROWS * DIM / 4;              // 262144
        const float4 v = (idx < ZQ) ? ((const float4*)z)[idx]
                                    : ((const float4*)mem)[idx - ZQ];
        ushort4 u; u.x = f2bf(v.x); u.y = f2bf(v.y);
        u.z = f2bf(v.z); u.w = f2bf(v.w);
        ((ushort4*)cand)[idx] = u;
    } else {
        const int row  = (bx - 5120) * 4 + ((int)threadIdx.x >> 6);
        const int lane = threadIdx.x & 63;
        if ((row & 255) != 255) {   // valid pair; also guards row 4095
            const float4 av = *(const float4*)(z + (size_t)row * DIM + lane * 4);
            const float4 bv = *(const float4*)(z + (size_t)(row + 1) * DIM + lane * 4);
            float sum = av.x * bv.x + av.y * bv.y + av.z * bv.z + av.w * bv.w;
#pragma unroll
            for (int off = 32; off > 0; off >>= 1) sum += __shfl_down(sum, off);
            if (lane == 0) pos[row] = sum * INV_T;
        }
    }
}

// Kernel A: R5's proven double-buffered MFMA flash-LSE main loop (verbatim:
// bf16 cand staging, XOR chunk swizzle, 1 barrier/stage, stride-33 merge)
// + cheap fused finisher: plain part stores -> one RELEASE RMW per block ->
// the single finisher per row-group does one ACQUIRE, reads 16KB of parts +
// precomputed pos (no 8MB z re-read: R8's regression), accumulates the loss.
__global__ __launch_bounds__(256) void mfma_lse_kernel(
    const ushort_t* __restrict__ cand,
    float* __restrict__ part_m, float* __restrict__ part_s,
    const float* __restrict__ pos, unsigned* __restrict__ ctrl,
    float* __restrict__ out)
{
    __shared__ __align__(16) char smem_raw[65536];       // 2x(A 16KB + B 16KB)
    __shared__ int sFlag;
    ushort_t* ldsA = (ushort_t*)smem_raw;                // [2][128*64]
    ushort_t* ldsB = ldsA + 2 * TM * BK;                 // [2][128*64]

    const int tid  = threadIdx.x;
    const int lane = tid & 63;
    const int w    = tid >> 6;        // wave 0..3
    const int wr   = w >> 1;          // wave row half (0/1)
    const int wc   = w & 1;           // wave col half
    const int quad = lane >> 4;
    const int ln   = lane & 15;
    const int bx   = blockIdx.x;
    const int rowBase = bx * TM;
    const int slice   = blockIdx.y;
    const int colSliceBase = slice * COLS_PER_SLICE;

    unsigned* grp  = ctrl;            // [32] row-group arrival counters
    unsigned* done = ctrl + 32;       // group-finisher count
    float*    loss = (float*)(ctrl + 33);

    // Staging geometry (R5): wave w covers tile rows [w*32, w*32+32),
    // lane l -> row srow + u*8, chunk c = (l&7)^(srow&7). 8 rows x 128B
    // contiguous per instruction (coalesced); XOR swizzle keeps fragment
    // ds_read_b128 conflict-free.
    const int srow = w * 32 + (lane >> 3);
    const int sc   = (lane & 7) ^ (srow & 7);
    const ushort_t* agp    = cand + (size_t)(rowBase + srow) * DIM + sc * 8;
    const ushort_t* bgbase = cand + (size_t)(colSliceBase + srow) * DIM + sc * 8;
    ushort_t* lab = ldsA + (w * 32) * BK;   // + buf*TM*BK + u*8*BK
    ushort_t* lbb = ldsB + (w * 32) * BK;

    auto stage = [&](int t, int kk, int buf) {
        const ushort_t* ag = agp + kk;
        const ushort_t* bg = bgbase + t * (TN * DIM) + kk;
        ushort_t* la = lab + buf * (TM * BK);
        ushort_t* lb = lbb + buf * (TM * BK);
#pragma unroll
        for (int u = 0; u < 4; ++u) {
            load_lds16(ag + u * 8 * DIM, la + u * 8 * BK);
            load_lds16(bg + u * 8 * DIM, lb + u * 8 * BK);
        }
    };

    float m2[16], s[16];
#pragma unroll
    for (int i = 0; i < 16; ++i) { m2[i] = -INFINITY; s[i] = 0.0f; }

    f32x4 acc[4][4];
#pragma unroll
    for (int ti = 0; ti < 4; ++ti)
#pragma unroll
        for (int tj = 0; tj < 4; ++tj) acc[ti][tj] = (f32x4)0.0f;

    stage(0, 0, 0);        // prologue: stage 0 -> buffer 0
    __syncthreads();

    for (int t = 0; t < TILES_PER_SLICE; ++t) {
#pragma unroll
        for (int q = 0; q < 4; ++q) {
            const int buf = q & 1;          // s = 4t+q -> buf = s&1 = q&1
            if (q < 3)                        stage(t,     (q + 1) * BK, buf ^ 1);
            else if (t + 1 < TILES_PER_SLICE) stage(t + 1, 0,            buf ^ 1);

            const ushort_t* la = ldsA + buf * (TM * BK);
            const ushort_t* lb = ldsB + buf * (TM * BK);
#pragma unroll
            for (int ks = 0; ks < 2; ++ks) {
                short8 af[4], bfr[4];
#pragma unroll
                for (int ti = 0; ti < 4; ++ti) {
                    const int row = wr * 64 + ti * 16 + ln;
                    const int p = row * 8 + ((ks * 4 + quad) ^ (row & 7));
                    af[ti] = *(const short8*)(la + p * 8);
                }
#pragma unroll
                for (int tj = 0; tj < 4; ++tj) {
                    const int col = wc * 64 + tj * 16 + ln;
                    const int p = col * 8 + ((ks * 4 + quad) ^ (col & 7));
                    bfr[tj] = *(const short8*)(lb + p * 8);
                }
#pragma unroll
                for (int ti = 0; ti < 4; ++ti)
#pragma unroll
                    for (int tj = 0; tj < 4; ++tj)
                        acc[ti][tj] = __builtin_amdgcn_mfma_f32_16x16x32_bf16(
                            af[ti], bfr[tj], acc[ti][tj], 0, 0, 0);
            }

            if (q == 3) {
                // Per-tile epilogue (runs while next tile's loads fly).
                // C/D layout: col = ln+16*tj+64*wc, row = quad*4+reg+16*ti+64*wr
                const int colBase = colSliceBase + t * TN;
                const bool hasDiag =
                    (colBase < rowBase + TM) && (rowBase < colBase + TN);
#pragma unroll
                for (int ti = 0; ti < 4; ++ti) {
#pragma unroll
                    for (int r = 0; r < 4; ++r) {
                        const int idx = ti * 4 + r;
                        float v0 = acc[ti][0][r], v1 = acc[ti][1][r];
                        float v2 = acc[ti][2][r], v3 = acc[ti][3][r];
                        if (hasDiag) {
                            const int grow = rowBase + wr * 64 + ti * 16 + quad * 4 + r;
                            const int gc0  = colBase + wc * 64 + ln;
                            if (gc0      == grow) v0 = -3.0e38f;  // mask self
                            if (gc0 + 16 == grow) v1 = -3.0e38f;
                            if (gc0 + 32 == grow) v2 = -3.0e38f;
                            if (gc0 + 48 == grow) v3 = -3.0e38f;
                        }
                        const float tmax = fmaxf(fmaxf(v0, v1), fmaxf(v2, v3)) * SCALE2;
                        const float mo = m2[idx];
                        const float mn = fmaxf(mo, tmax);
                        const float sc2 = __builtin_amdgcn_exp2f(mo - mn);
                        s[idx] = s[idx] * sc2
                               + __builtin_amdgcn_exp2f(fmaf(v0, SCALE2, -mn))
                               + __builtin_amdgcn_exp2f(fmaf(v1, SCALE2, -mn))
                               + __builtin_amdgcn_exp2f(fmaf(v2, SCALE2, -mn))
                               + __builtin_amdgcn_exp2f(fmaf(v3, SCALE2, -mn));
                        m2[idx] = mn;
                        acc[ti][0][r] = 0.0f; acc[ti][1][r] = 0.0f;
                        acc[ti][2][r] = 0.0f; acc[ti][3][r] = 0.0f;
                    }
                }
            }
            __syncthreads();   // publishes prefetched stage; frees old buffer
        }
    }

    // Cross-lane merge: 32 partials per row (16 ln x 2 wc), stride-33 overlay.
    float* smf = (float*)smem_raw;         // [128][33] m partials
    float* ssf = smf + TM * MERGE_STRIDE;  // [128][33] s partials
    const int p = wc * 16 + ln;
#pragma unroll
    for (int ti = 0; ti < 4; ++ti)
#pragma unroll
        for (int r = 0; r < 4; ++r) {
            const int rl = wr * 64 + ti * 16 + quad * 4 + r;
            smf[rl * MERGE_STRIDE + p] = m2[ti * 4 + r];
            ssf[rl * MERGE_STRIDE + p] = s[ti * 4 + r];
        }
    __syncthreads();
    if (tid < TM) {
        float M = -INFINITY;
#pragma unroll
        for (int x = 0; x < 32; ++x) M = fmaxf(M, smf[tid * MERGE_STRIDE + x]);
        float S = 0.0f;
#pragma unroll
        for (int x = 0; x < 32; ++x)
            S += ssf[tid * MERGE_STRIDE + x]
               * __builtin_amdgcn_exp2f(smf[tid * MERGE_STRIDE + x] - M);
        // Plain stores; published by the release RMW below.
        part_m[(size_t)(rowBase + tid) * NSLICE + slice] = M;
        part_s[(size_t)(rowBase + tid) * NSLICE + slice] = S;
    }
    __syncthreads();

    // Arrival: release-publish this block's part stores (dirty-line
    // writeback only; no invalidation for the 480 non-finisher blocks).
    if (tid == 0) {
        const unsigned o = __hip_atomic_fetch_add(
            grp + bx, 1u, __ATOMIC_RELEASE, __HIP_MEMORY_SCOPE_AGENT);
        sFlag = (o == NSLICE - 1);
    }
    __syncthreads();
    if (!sFlag) return;

    // Finisher (1 per row-group, 32 total): one acquire, then plain loads of
    // 16KB parts + 512B precomputed pos. No z re-read (R8's mistake).
    if (tid == 0)
        (void)__hip_atomic_load(grp + bx, __ATOMIC_ACQUIRE,
                                __HIP_MEMORY_SCOPE_AGENT);
    __syncthreads();   // acquire ordered before the loads below

    float* red = (float*)smem_raw;         // [256] reduction overlay
    float local = 0.0f;
    if (tid < TM) {
        const int row = rowBase + tid;
        if ((row & 255) != 255) {
            const float4* pm4 = (const float4*)(part_m + (size_t)row * NSLICE);
            const float4* ps4 = (const float4*)(part_s + (size_t)row * NSLICE);
            float pm[NSLICE], ps[NSLICE];
#pragma unroll
            for (int x = 0; x < 4; ++x) {
                const float4 mv = pm4[x], sv = ps4[x];
                pm[x*4+0]=mv.x; pm[x*4+1]=mv.y; pm[x*4+2]=mv.z; pm[x*4+3]=mv.w;
                ps[x*4+0]=sv.x; ps[x*4+1]=sv.y; ps[x*4+2]=sv.z; ps[x*4+3]=sv.w;
            }
            float M = -INFINITY, S = 0.0f;
#pragma unroll
            for (int x = 0; x < NSLICE; ++x) M = fmaxf(M, pm[x]);
#pragma unroll
            for (int x = 0; x < NSLICE; ++x)
                S += ps[x] * __builtin_amdgcn_exp2f(pm[x] - M);
            const float lse = LN2 * (M + __builtin_amdgcn_logf(S));
            local = lse - pos[row];        // pos precomputed by prep kernel
        }
    }
    red[tid] = local;
    __syncthreads();
    for (int st = 128; st > 0; st >>= 1) {
        if (tid < st) red[tid] += red[tid + st];
        __syncthreads();
    }
    if (tid == 0) {
        atomicAdd(loss, red[0]);           // device-scope float atomic
        const unsigned od = __hip_atomic_fetch_add(
            done, 1u, __ATOMIC_ACQ_REL, __HIP_MEMORY_SCOPE_AGENT);
        if (od == NROWS / TM - 1) {
            const float total = __hip_atomic_load(loss, __ATOMIC_RELAXED,
                                                  __HIP_MEMORY_SCOPE_AGENT);
            out[0] = total / 4080.0f;      // B*(L-1) valid pairs
        }
    }
}

extern "C" void kernel_launch(void* const* d_in, const int* in_sizes, int n_in,
                              void* d_out, int out_size, void* d_ws, size_t ws_size,
                              hipStream_t stream) {
    const float* z   = (const float*)d_in[0];   // [4096, 256]
    // d_in[1] = va_values: dead code in the reference, unused.
    const float* mem = (const float*)d_in[2];   // [16384, 256]

    // ws layout: cand bf16 [20480*256] | part_m f32 [4096*16]
    //          | part_s f32 [4096*16] | pos f32 [4096] | ctrl u32 [64]
    ushort_t* cand = (ushort_t*)d_ws;
    float* part_m  = (float*)(cand + (size_t)NCAND * DIM);
    float* part_s  = part_m + (size_t)NROWS * NSLICE;
    float* pos     = part_s + (size_t)NROWS * NSLICE;
    unsigned* ctrl = (unsigned*)(pos + NROWS);

    prep_kernel<<<dim3(6144), dim3(256), 0, stream>>>(z, mem, cand, pos, ctrl);
    mfma_lse_kernel<<<dim3(NROWS / TM, NSLICE), dim3(256), 0, stream>>>(
        cand, part_m, part_s, pos, ctrl, (float*)d_out);
}